// Round 12
// baseline (246.322 us; speedup 1.0000x reference)
//
#include <hip/hip_runtime.h>

typedef float f32x4 __attribute__((ext_vector_type(4)));
typedef short bf16x8 __attribute__((ext_vector_type(8)));

#define NTOK 8192
#define DIM  1024
#define NE   8
#define NH   512
#define NO   1024

static __device__ __forceinline__ unsigned short f2bf(float f) {
  unsigned u = __float_as_uint(f);
  u += 0x7fffu + ((u >> 16) & 1u);
  return (unsigned short)(u >> 16);
}
static __device__ __forceinline__ unsigned pk2(float a, float b) {
  return (unsigned)f2bf(a) | ((unsigned)f2bf(b) << 16);
}

static __device__ __forceinline__ f32x4 mfma_bf16(bf16x8 a, bf16x8 b, f32x4 c) {
  return __builtin_amdgcn_mfma_f32_16x16x32_bf16(a, b, c, 0, 0, 0);
}

// ---------------------------------------------------------------------------
// Gate: fp64 logits -> top-4 bitmask byte per token. Also zeroes d_out
// (16 floats/thread) so moe_ffn can atomicAdd partials.
// ---------------------------------------------------------------------------
__global__ __launch_bounds__(256) void gate_kernel(
    const float* __restrict__ x, const float* __restrict__ wg,
    unsigned char* __restrict__ msk8, float* __restrict__ out)
{
  {
    size_t t = (size_t)blockIdx.x * 256 + threadIdx.x;
    float4* op = (float4*)(out + t * 16);
    float4 z4 = {0.f, 0.f, 0.f, 0.f};
    op[0] = z4; op[1] = z4; op[2] = z4; op[3] = z4;
  }
  const int lane = threadIdx.x & 63;
  const int wv = threadIdx.x >> 6;
  const int n = blockIdx.x * 4 + wv;
  const float* xr = x + (size_t)n * DIM;
  float4 v[4];
#pragma unroll
  for (int i = 0; i < 4; ++i) v[i] = *(const float4*)(xr + i * 256 + lane * 4);
  double logit[NE];
#pragma unroll
  for (int e = 0; e < NE; ++e) {
    const float* wr = wg + e * DIM;
    double s = 0.0;
#pragma unroll
    for (int i = 0; i < 4; ++i) {
      float4 g = *(const float4*)(wr + i * 256 + lane * 4);
      s += (double)v[i].x * g.x + (double)v[i].y * g.y +
           (double)v[i].z * g.z + (double)v[i].w * g.w;
    }
#pragma unroll
    for (int off = 32; off; off >>= 1) s += __shfl_down(s, off);
    logit[e] = s;
  }
  if (lane == 0) {
    unsigned sel = 0;
#pragma unroll
    for (int t = 0; t < 4; ++t) {
      int best = 0; double bv = -1.0e300;
#pragma unroll
      for (int e = 0; e < NE; ++e)
        if (!((sel >> e) & 1) && logit[e] > bv) { bv = logit[e]; best = e; }
      sel |= 1u << best;
    }
    msk8[n] = (unsigned char)sel;
  }
}

// ---------------------------------------------------------------------------
// Weight packs (unchanged): fragment-major bf16.
// ---------------------------------------------------------------------------
__global__ __launch_bounds__(256) void pack_w1_kernel(
    const float* __restrict__ w1, unsigned short* __restrict__ w1p)
{
  int t = blockIdx.x * 256 + threadIdx.x;
  int lane = t & 63, ks = (t >> 6) & 31, nt = (t >> 11) & 31, e = t >> 16;
  int r = nt * 16 + (lane & 15);
  int c = ks * 32 + (lane >> 4) * 8;
  const float* src = w1 + ((size_t)(e * 512 + r)) * 1024 + c;
  float4 f0 = *(const float4*)src;
  float4 f1 = *(const float4*)(src + 4);
  uint4 v;
  v.x = pk2(f0.x, f0.y); v.y = pk2(f0.z, f0.w);
  v.z = pk2(f1.x, f1.y); v.w = pk2(f1.z, f1.w);
  *(uint4*)(w1p + (size_t)t * 8) = v;
}

__global__ __launch_bounds__(256) void pack_w2_kernel(
    const float* __restrict__ w2, unsigned short* __restrict__ w2p)
{
  int t = blockIdx.x * 256 + threadIdx.x;
  int lane = t & 63, ks = (t >> 6) & 15, ot = (t >> 10) & 63, e = t >> 16;
  int o = ot * 16 + (lane & 15);
  int h = ks * 32 + (lane >> 4) * 8;
  const float* src = w2 + ((size_t)(e * 1024 + o)) * 512 + h;
  float4 f0 = *(const float4*)src;
  float4 f1 = *(const float4*)(src + 4);
  uint4 v;
  v.x = pk2(f0.x, f0.y); v.y = pk2(f0.z, f0.w);
  v.z = pk2(f1.x, f1.y); v.w = pk2(f1.z, f1.w);
  *(uint4*)(w2p + (size_t)t * 8) = v;
}

// ---------------------------------------------------------------------------
// Fused MoE FFN, round 12: R8 geometry + IN-REGION register prefetch of the
// B streams (the only change vs R8). No cross-barrier motion, no setprio.
//   GEMM1: full H; wave owns 4m x {wv, wv+16}; depth-3 prefetch (6 in flight)
//   GEMM2: per H-chunk hh; wave owns 4m x 4n; depth-2 prefetch (8 in flight)
// Per block: 4 experts x (1 MB w1 + 1 MB w2), each byte loaded exactly once.
// Partials (2/element) via atomicAdd; out zeroed by gate.
// xs 128 KB + hs 32 KB = 160 KB. Replay-proven 2-barrier template.
// ---------------------------------------------------------------------------
__global__ __launch_bounds__(1024, 4) void moe_ffn(
    const float* __restrict__ x, const unsigned short* __restrict__ w1p,
    const unsigned short* __restrict__ w2p, const unsigned char* __restrict__ msk8,
    float* __restrict__ out)
{
  __shared__ unsigned short xs[128 * 64 * 8];  // 128 KB: frag f = ks*4+m
  __shared__ unsigned short hs[32 * 64 * 8];   // 32 KB: frag fr = ks2*4+m

  const int tid = threadIdx.x;
  const int lane = tid & 63;
  const int wv = tid >> 6;
  const int row0 = (blockIdx.x >> 1) * 64;
  const int eq = blockIdx.x & 1;               // expert quad
  const int arow = lane & 15;
  const int kch = lane >> 4;

  // ---- stage X: 64 rows x 1024 f32 -> bf16 fragment-major ---------------
#pragma unroll
  for (int i = 0; i < 8; ++i) {
    int c = i * 1024 + tid;          // 64 rows x 128 chunks-of-8
    int r = c >> 7;
    int ch = c & 127;
    const float* src = x + (size_t)(row0 + r) * DIM + ch * 8;
    float4 f0 = *(const float4*)src;
    float4 f1 = *(const float4*)(src + 4);
    uint4 v;
    v.x = pk2(f0.x, f0.y); v.y = pk2(f0.z, f0.w);
    v.z = pk2(f1.x, f1.y); v.w = pk2(f1.z, f1.w);
    int f = (ch >> 2) * 4 + (r >> 4);            // ks*4 + m
    int l = ((ch & 3) << 4) | (r & 15);          // kch<<4 | row
    *(uint4*)(xs + ((size_t)(f * 64 + l)) * 8) = v;
  }
  unsigned mb[4];
#pragma unroll
  for (int m = 0; m < 4; ++m)
    mb[m] = *(const unsigned*)(msk8 + row0 + m * 16 + kch * 4);
  __syncthreads();

  const unsigned short* xp = xs + lane * 8;
  const unsigned short* hp = hs + lane * 8;

  f32x4 oacc[4][4];
#pragma unroll
  for (int m = 0; m < 4; ++m)
#pragma unroll
    for (int n = 0; n < 4; ++n) oacc[m][n] = f32x4{0.f, 0.f, 0.f, 0.f};

#pragma unroll 1
  for (int el = 0; el < 4; ++el) {
    const int e = eq * 4 + el;

    // ---- GEMM1: full H; wave = 4m x {wv, wv+16}; B unique ---------------
    // depth-3 register prefetch, entirely within this barrier region
    f32x4 hacc0[4], hacc1[4];
#pragma unroll
    for (int m = 0; m < 4; ++m) {
      hacc0[m] = f32x4{0.f, 0.f, 0.f, 0.f};
      hacc1[m] = f32x4{0.f, 0.f, 0.f, 0.f};
    }
    const unsigned short* pb0 = w1p + ((size_t)(e * 32 + wv) * 32) * 512 + lane * 8;
    const unsigned short* pb1 = pb0 + (size_t)16 * 32 * 512;
    bf16x8 b0c  = *(const bf16x8*)(pb0);
    bf16x8 b1c  = *(const bf16x8*)(pb1);
    bf16x8 b0n1 = *(const bf16x8*)(pb0 + 512);
    bf16x8 b1n1 = *(const bf16x8*)(pb1 + 512);
    bf16x8 b0n2 = *(const bf16x8*)(pb0 + 1024);
    bf16x8 b1n2 = *(const bf16x8*)(pb1 + 1024);
#pragma unroll 4
    for (int ks = 0; ks < 32; ++ks) {
      bf16x8 t0 = b0c, t1 = b1c;
      b0c = b0n1; b1c = b1n1;
      b0n1 = b0n2; b1n1 = b1n2;
      int kp = (ks + 3 < 32) ? ks + 3 : 31;    // uniform scalar clamp
      b0n2 = *(const bf16x8*)(pb0 + kp * 512);
      b1n2 = *(const bf16x8*)(pb1 + kp * 512);
#pragma unroll
      for (int m = 0; m < 4; ++m) {
        bf16x8 a = *(const bf16x8*)(xp + (ks * 4 + m) * 512);
        hacc0[m] = mfma_bf16(a, t0, hacc0[m]);
        hacc1[m] = mfma_bf16(a, t1, hacc1[m]);
      }
    }

    // ---- two H-chunks: epilogue -> hs -> GEMM2 (hh fully unrolled) ------
#pragma unroll
    for (int hh = 0; hh < 2; ++hh) {
      __syncthreads();   // all waves done reading hs (previous chunk/expert)

      // epilogue: relu * mask-bit -> hs fragments (chunk hh)
#pragma unroll
      for (int m = 0; m < 4; ++m)
#pragma unroll
        for (int j = 0; j < 4; ++j) {
          float hv = hh ? hacc1[m][j] : hacc0[m][j];   // static after unroll
          float v = fmaxf(hv, 0.0f);
          v = ((mb[m] >> (j * 8 + e)) & 1u) ? v : 0.0f;
          int f = (wv >> 1) * 4 + m;
          int l2 = (((wv & 1) * 2 + (arow >> 3)) << 4) | (kch * 4 + j);
          hs[((size_t)(f * 64 + l2)) * 8 + (arow & 7)] = f2bf(v);
        }
      __syncthreads();   // hs chunk ready

      // GEMM2 chunk: oacc[4m][4n] += hs_chunk @ W2[e][wv*4..+4, hh-half]
      // depth-2 register prefetch, entirely within this barrier region
      const unsigned short* pc =
          w2p + ((size_t)((e * 64 + wv * 4) * 16 + hh * 8)) * 512 + lane * 8;
      bf16x8 c0c = *(const bf16x8*)(pc);
      bf16x8 c1c = *(const bf16x8*)(pc + 8192);
      bf16x8 c2c = *(const bf16x8*)(pc + 16384);
      bf16x8 c3c = *(const bf16x8*)(pc + 24576);
      bf16x8 c0n = *(const bf16x8*)(pc + 512);
      bf16x8 c1n = *(const bf16x8*)(pc + 8704);
      bf16x8 c2n = *(const bf16x8*)(pc + 16896);
      bf16x8 c3n = *(const bf16x8*)(pc + 25088);
#pragma unroll 2
      for (int ks2 = 0; ks2 < 8; ++ks2) {
        bf16x8 t0 = c0c, t1 = c1c, t2 = c2c, t3 = c3c;
        c0c = c0n; c1c = c1n; c2c = c2n; c3c = c3n;
        int kp = (ks2 + 2 < 8) ? ks2 + 2 : 7;
        c0n = *(const bf16x8*)(pc + kp * 512);
        c1n = *(const bf16x8*)(pc + 8192 + kp * 512);
        c2n = *(const bf16x8*)(pc + 16384 + kp * 512);
        c3n = *(const bf16x8*)(pc + 24576 + kp * 512);
        bf16x8 a0 = *(const bf16x8*)(hp + (ks2 * 4 + 0) * 512);
        bf16x8 a1 = *(const bf16x8*)(hp + (ks2 * 4 + 1) * 512);
        bf16x8 a2 = *(const bf16x8*)(hp + (ks2 * 4 + 2) * 512);
        bf16x8 a3 = *(const bf16x8*)(hp + (ks2 * 4 + 3) * 512);
        oacc[0][0] = mfma_bf16(a0, t0, oacc[0][0]);
        oacc[1][0] = mfma_bf16(a1, t0, oacc[1][0]);
        oacc[2][0] = mfma_bf16(a2, t0, oacc[2][0]);
        oacc[3][0] = mfma_bf16(a3, t0, oacc[3][0]);
        oacc[0][1] = mfma_bf16(a0, t1, oacc[0][1]);
        oacc[1][1] = mfma_bf16(a1, t1, oacc[1][1]);
        oacc[2][1] = mfma_bf16(a2, t1, oacc[2][1]);
        oacc[3][1] = mfma_bf16(a3, t1, oacc[3][1]);
        oacc[0][2] = mfma_bf16(a0, t2, oacc[0][2]);
        oacc[1][2] = mfma_bf16(a1, t2, oacc[1][2]);
        oacc[2][2] = mfma_bf16(a2, t2, oacc[2][2]);
        oacc[3][2] = mfma_bf16(a3, t2, oacc[3][2]);
        oacc[0][3] = mfma_bf16(a0, t3, oacc[0][3]);
        oacc[1][3] = mfma_bf16(a1, t3, oacc[1][3]);
        oacc[2][3] = mfma_bf16(a2, t3, oacc[2][3]);
        oacc[3][3] = mfma_bf16(a3, t3, oacc[3][3]);
      }
    }
  }

  // ---- atomic partial-sum into out (2 partials/element, commutative) -----
#pragma unroll
  for (int m = 0; m < 4; ++m)
#pragma unroll
    for (int n = 0; n < 4; ++n)
#pragma unroll
      for (int j = 0; j < 4; ++j) {
        int row = row0 + m * 16 + kch * 4 + j;
        int col = (wv * 4 + n) * 16 + arow;
        atomicAdd(&out[(size_t)row * NO + col], oacc[m][n][j]);
      }
}

extern "C" void kernel_launch(void* const* d_in, const int* in_sizes, int n_in,
                              void* d_out, int out_size, void* d_ws, size_t ws_size,
                              hipStream_t stream) {
  (void)in_sizes; (void)n_in; (void)out_size; (void)ws_size;
  const float* x  = (const float*)d_in[0];
  const float* wg = (const float*)d_in[1];
  const float* w1 = (const float*)d_in[2];
  const float* w2 = (const float*)d_in[3];
  float* out = (float*)d_out;
  char* ws = (char*)d_ws;
  unsigned short* w1p = (unsigned short*)ws;                        // 8 MB
  unsigned short* w2p = (unsigned short*)(ws + ((size_t)8 << 20));  // 8 MB
  unsigned char* msk8 = (unsigned char*)(ws + ((size_t)16 << 20));  // 8 KB

  gate_kernel<<<2048, 256, 0, stream>>>(x, wg, msk8, out);
  pack_w1_kernel<<<2048, 256, 0, stream>>>(w1, w1p);
  pack_w2_kernel<<<2048, 256, 0, stream>>>(w2, w2p);
  moe_ffn<<<256, 1024, 0, stream>>>(x, w1p, w2p, msk8, out);
}

// Round 13
// 200.192 us; speedup vs baseline: 1.2304x; 1.2304x over previous
//
#include <hip/hip_runtime.h>

typedef float f32x4 __attribute__((ext_vector_type(4)));
typedef short bf16x8 __attribute__((ext_vector_type(8)));

#define NTOK 8192
#define DIM  1024
#define NE   8
#define NH   512
#define NO   1024

static __device__ __forceinline__ unsigned short f2bf(float f) {
  unsigned u = __float_as_uint(f);
  u += 0x7fffu + ((u >> 16) & 1u);
  return (unsigned short)(u >> 16);
}
static __device__ __forceinline__ unsigned pk2(float a, float b) {
  return (unsigned)f2bf(a) | ((unsigned)f2bf(b) << 16);
}

static __device__ __forceinline__ f32x4 mfma_bf16(bf16x8 a, bf16x8 b, f32x4 c) {
  return __builtin_amdgcn_mfma_f32_16x16x32_bf16(a, b, c, 0, 0, 0);
}

// ---------------------------------------------------------------------------
// Gate: fp64 logits -> top-4 bitmask byte per token. Also zeroes d_out
// (16 floats/thread) so moe_ffn can atomicAdd partials.
// ---------------------------------------------------------------------------
__global__ __launch_bounds__(256) void gate_kernel(
    const float* __restrict__ x, const float* __restrict__ wg,
    unsigned char* __restrict__ msk8, float* __restrict__ out)
{
  {
    size_t t = (size_t)blockIdx.x * 256 + threadIdx.x;
    float4* op = (float4*)(out + t * 16);
    float4 z4 = {0.f, 0.f, 0.f, 0.f};
    op[0] = z4; op[1] = z4; op[2] = z4; op[3] = z4;
  }
  const int lane = threadIdx.x & 63;
  const int wv = threadIdx.x >> 6;
  const int n = blockIdx.x * 4 + wv;
  const float* xr = x + (size_t)n * DIM;
  float4 v[4];
#pragma unroll
  for (int i = 0; i < 4; ++i) v[i] = *(const float4*)(xr + i * 256 + lane * 4);
  double logit[NE];
#pragma unroll
  for (int e = 0; e < NE; ++e) {
    const float* wr = wg + e * DIM;
    double s = 0.0;
#pragma unroll
    for (int i = 0; i < 4; ++i) {
      float4 g = *(const float4*)(wr + i * 256 + lane * 4);
      s += (double)v[i].x * g.x + (double)v[i].y * g.y +
           (double)v[i].z * g.z + (double)v[i].w * g.w;
    }
#pragma unroll
    for (int off = 32; off; off >>= 1) s += __shfl_down(s, off);
    logit[e] = s;
  }
  if (lane == 0) {
    unsigned sel = 0;
#pragma unroll
    for (int t = 0; t < 4; ++t) {
      int best = 0; double bv = -1.0e300;
#pragma unroll
      for (int e = 0; e < NE; ++e)
        if (!((sel >> e) & 1) && logit[e] > bv) { bv = logit[e]; best = e; }
      sel |= 1u << best;
    }
    msk8[n] = (unsigned char)sel;
  }
}

// ---------------------------------------------------------------------------
// Merged weight pack: fragment-major bf16 for w1 and w2 in one launch.
// w1p [e][nt:32][ks:32][lane:64][j:8]; elem = w1[e][nt*16+(l&15)][ks*32+(l>>4)*8+j]
// w2p [e][ot:64][ks2:16][lane:64][j:8]; elem = w2[e][ot*16+(l&15)][ks2*32+(l>>4)*8+j]
// Blocks 0..2047 pack w1; 2048..4095 pack w2 (block-uniform branch).
// ---------------------------------------------------------------------------
__global__ __launch_bounds__(256) void pack_w_kernel(
    const float* __restrict__ w1, const float* __restrict__ w2,
    unsigned short* __restrict__ w1p, unsigned short* __restrict__ w2p)
{
  int t = blockIdx.x * 256 + threadIdx.x;
  if (t < 524288) {
    int lane = t & 63, ks = (t >> 6) & 31, nt = (t >> 11) & 31, e = t >> 16;
    int r = nt * 16 + (lane & 15);
    int c = ks * 32 + (lane >> 4) * 8;
    const float* src = w1 + ((size_t)(e * 512 + r)) * 1024 + c;
    float4 f0 = *(const float4*)src;
    float4 f1 = *(const float4*)(src + 4);
    uint4 v;
    v.x = pk2(f0.x, f0.y); v.y = pk2(f0.z, f0.w);
    v.z = pk2(f1.x, f1.y); v.w = pk2(f1.z, f1.w);
    *(uint4*)(w1p + (size_t)t * 8) = v;
  } else {
    t -= 524288;
    int lane = t & 63, ks = (t >> 6) & 15, ot = (t >> 10) & 63, e = t >> 16;
    int o = ot * 16 + (lane & 15);
    int h = ks * 32 + (lane >> 4) * 8;
    const float* src = w2 + ((size_t)(e * 1024 + o)) * 512 + h;
    float4 f0 = *(const float4*)src;
    float4 f1 = *(const float4*)(src + 4);
    uint4 v;
    v.x = pk2(f0.x, f0.y); v.y = pk2(f0.z, f0.w);
    v.z = pk2(f1.x, f1.y); v.w = pk2(f1.z, f1.w);
    *(uint4*)(w2p + (size_t)t * 8) = v;
  }
}

// ---------------------------------------------------------------------------
// Fused MoE FFN — round-6 champion structure, byte-identical inner loops.
// BM=64 tokens, H-SPLIT (z = hidden half), 16 waves, zero cross-wave B dup:
//   GEMM1: wave = 4m x 1n  (16 waves <-> 16 H-frags of the half)
//   GEMM2: wave = 4m x 4n  (16 waves <-> 64 O-frags), partial over H-half
// Only change vs R6: XCD-pinned block swizzle — z = (bid&7)>>2 so all z=0
// blocks live on XCDs 0-3, z=1 on 4-7 (halves per-XCD L2 working set).
// Partials (2/element) via atomicAdd; out zeroed by gate.
// xs 128 KB + hs 32 KB = 160 KB LDS.
// ---------------------------------------------------------------------------
__global__ __launch_bounds__(1024, 4) void moe_ffn(
    const float* __restrict__ x, const unsigned short* __restrict__ w1p,
    const unsigned short* __restrict__ w2p, const unsigned char* __restrict__ msk8,
    float* __restrict__ out)
{
  __shared__ unsigned short xs[128 * 64 * 8];  // 128 KB: frag f = ks*4+m
  __shared__ unsigned short hs[32 * 64 * 8];   // 32 KB: frag f = ks2*4+m

  const int tid = threadIdx.x;
  const int lane = tid & 63;
  const int wv = tid >> 6;
  const int bid = blockIdx.x;
  const int z = (bid & 7) >> 2;                        // H-half, XCD-pinned
  const int row0 = (((bid >> 3) << 2) | (bid & 3)) * 64;
  const int arow = lane & 15;
  const int kch = lane >> 4;

  // ---- stage X: 64 rows x 1024 f32 -> bf16 fragment-major ---------------
#pragma unroll
  for (int i = 0; i < 8; ++i) {
    int c = i * 1024 + tid;          // 64 rows x 128 chunks-of-8
    int r = c >> 7;
    int ch = c & 127;
    const float* src = x + (size_t)(row0 + r) * DIM + ch * 8;
    float4 f0 = *(const float4*)src;
    float4 f1 = *(const float4*)(src + 4);
    uint4 v;
    v.x = pk2(f0.x, f0.y); v.y = pk2(f0.z, f0.w);
    v.z = pk2(f1.x, f1.y); v.w = pk2(f1.z, f1.w);
    int f = (ch >> 2) * 4 + (r >> 4);            // ks*4 + m
    int l = ((ch & 3) << 4) | (r & 15);          // kch<<4 | row
    *(uint4*)(xs + ((size_t)(f * 64 + l)) * 8) = v;
  }
  __syncthreads();

  const unsigned short* xp = xs + lane * 8;
  const unsigned short* hp = hs + lane * 8;

  f32x4 oacc[4][4];
#pragma unroll
  for (int m = 0; m < 4; ++m)
#pragma unroll
    for (int n = 0; n < 4; ++n) oacc[m][n] = f32x4{0.f, 0.f, 0.f, 0.f};

  for (int e = 0; e < NE; ++e) {
    // ---- GEMM1: wave owns H-frag (z*16+wv); 4m x 1n; B unique per wave --
    f32x4 hacc[4];
#pragma unroll
    for (int m = 0; m < 4; ++m) hacc[m] = f32x4{0.f, 0.f, 0.f, 0.f};

    const unsigned short* pb =
        w1p + ((size_t)(e * 32 + z * 16 + wv) * 32) * 512 + lane * 8;
#pragma unroll 4
    for (int ks = 0; ks < 32; ++ks) {
      bf16x8 b = *(const bf16x8*)(pb + ks * 512);
#pragma unroll
      for (int m = 0; m < 4; ++m) {
        bf16x8 a = *(const bf16x8*)(xp + (ks * 4 + m) * 512);
        hacc[m] = mfma_bf16(a, b, hacc[m]);
      }
    }
    __syncthreads();   // all waves done reading hs (previous expert GEMM2)

    // ---- epilogue: relu * mask-bit -> hs fragments ----------------------
#pragma unroll
    for (int m = 0; m < 4; ++m) {
      const unsigned mb = *(const unsigned*)(msk8 + row0 + m * 16 + kch * 4);
#pragma unroll
      for (int j = 0; j < 4; ++j) {
        float v = fmaxf(hacc[m][j], 0.0f);
        v = ((mb >> (j * 8 + e)) & 1u) ? v : 0.0f;
        int f = (wv >> 1) * 4 + m;
        int l2 = (((wv & 1) * 2 + (arow >> 3)) << 4) | (kch * 4 + j);
        hs[((size_t)(f * 64 + l2)) * 8 + (arow & 7)] = f2bf(v);
      }
    }
    __syncthreads();   // hs ready

    // ---- GEMM2: out[64 x 1024] += hs_half @ W2[e][:, half]; 4m x 4n -----
    const unsigned short* pc =
        w2p + ((size_t)((e * 64 + wv * 4) * 16 + z * 8)) * 512 + lane * 8;
#pragma unroll 2
    for (int ks2 = 0; ks2 < 8; ++ks2) {
      bf16x8 a0 = *(const bf16x8*)(hp + (ks2 * 4 + 0) * 512);
      bf16x8 a1 = *(const bf16x8*)(hp + (ks2 * 4 + 1) * 512);
      bf16x8 a2 = *(const bf16x8*)(hp + (ks2 * 4 + 2) * 512);
      bf16x8 a3 = *(const bf16x8*)(hp + (ks2 * 4 + 3) * 512);
#pragma unroll
      for (int n = 0; n < 4; ++n) {
        bf16x8 b = *(const bf16x8*)(pc + (size_t)n * 8192 + ks2 * 512);
        oacc[0][n] = mfma_bf16(a0, b, oacc[0][n]);
        oacc[1][n] = mfma_bf16(a1, b, oacc[1][n]);
        oacc[2][n] = mfma_bf16(a2, b, oacc[2][n]);
        oacc[3][n] = mfma_bf16(a3, b, oacc[3][n]);
      }
    }
  }

  // ---- atomic partial-sum into out (2 partials/element, commutative) -----
#pragma unroll
  for (int m = 0; m < 4; ++m)
#pragma unroll
    for (int n = 0; n < 4; ++n)
#pragma unroll
      for (int j = 0; j < 4; ++j) {
        int row = row0 + m * 16 + kch * 4 + j;
        int col = (wv * 4 + n) * 16 + arow;
        atomicAdd(&out[(size_t)row * NO + col], oacc[m][n][j]);
      }
}

extern "C" void kernel_launch(void* const* d_in, const int* in_sizes, int n_in,
                              void* d_out, int out_size, void* d_ws, size_t ws_size,
                              hipStream_t stream) {
  (void)in_sizes; (void)n_in; (void)out_size; (void)ws_size;
  const float* x  = (const float*)d_in[0];
  const float* wg = (const float*)d_in[1];
  const float* w1 = (const float*)d_in[2];
  const float* w2 = (const float*)d_in[3];
  float* out = (float*)d_out;
  char* ws = (char*)d_ws;
  unsigned short* w1p = (unsigned short*)ws;                        // 8 MB
  unsigned short* w2p = (unsigned short*)(ws + ((size_t)8 << 20));  // 8 MB
  unsigned char* msk8 = (unsigned char*)(ws + ((size_t)16 << 20));  // 8 KB

  gate_kernel<<<2048, 256, 0, stream>>>(x, wg, msk8, out);
  pack_w_kernel<<<4096, 256, 0, stream>>>(w1, w2, w1p, w2p);
  moe_ffn<<<256, 1024, 0, stream>>>(x, w1p, w2p, msk8, out);
}